// Round 14
// baseline (51.271 us; speedup 1.0000x reference)
//
#include <hip/hip_runtime.h>
#include <hip/hip_bf16.h>
#include <cstddef>

typedef __attribute__((ext_vector_type(8))) short bf16x8;
typedef __attribute__((ext_vector_type(4))) float f32x4;

__device__ __forceinline__ float4 ld4(const float* p) { return *(const float4*)p; }
__device__ __forceinline__ unsigned short f2bf(float v) {
  __hip_bfloat16 h = __float2bfloat16(v);
  return *(unsigned short*)&h;
}

__device__ __forceinline__ bf16x8 pack8(float v0, float v1, float v2, float v3,
                                        float v4, float v5, float v6, float v7) {
  bf16x8 r;
  r[0] = (short)f2bf(v0); r[1] = (short)f2bf(v1);
  r[2] = (short)f2bf(v2); r[3] = (short)f2bf(v3);
  r[4] = (short)f2bf(v4); r[5] = (short)f2bf(v5);
  r[6] = (short)f2bf(v6); r[7] = (short)f2bf(v7);
  return r;
}
// 8 contiguous fp32 -> bf16x8 (A-fragments: weight rows)
__device__ __forceinline__ bf16x8 cfrag(const float* __restrict__ p) {
  float4 a = ld4(p), b = ld4(p + 4);
  return pack8(a.x, a.y, a.z, a.w, b.x, b.y, b.z, b.w);
}
// 8 strided fp32 -> bf16x8 (B-fragments: input channel walk at fixed pixel)
__device__ __forceinline__ bf16x8 gfrag(const float* __restrict__ p, int stride) {
  float v0 = p[0], v1 = p[stride], v2 = p[2 * stride], v3 = p[3 * stride];
  float v4 = p[4 * stride], v5 = p[5 * stride], v6 = p[6 * stride], v7 = p[7 * stride];
  return pack8(v0, v1, v2, v3, v4, v5, v6, v7);
}
__device__ __forceinline__ bf16x8 gfrag_guard(const float* __restrict__ p, int stride, bool ok) {
  float v0 = ok ? p[0] : 0.f, v1 = ok ? p[stride] : 0.f;
  float v2 = ok ? p[2 * stride] : 0.f, v3 = ok ? p[3 * stride] : 0.f;
  float v4 = ok ? p[4 * stride] : 0.f, v5 = ok ? p[5 * stride] : 0.f;
  float v6 = ok ? p[6 * stride] : 0.f, v7 = ok ? p[7 * stride] : 0.f;
  return pack8(v0, v1, v2, v3, v4, v5, v6, v7);
}

// 2x bilinear upsample of one 2x2 quad (three halo-resolved source rows).
__device__ __forceinline__ void up_quad_rows(const float* __restrict__ s0,
                                             const float* __restrict__ s1,
                                             const float* __restrict__ s2,
                                             int qx, int W, float* __restrict__ dst, int pitch) {
  int cm = qx > 0 ? qx - 1 : 0, cp = qx < W - 1 ? qx + 1 : W - 1;
  float tA0 = 0.25f * s0[cm] + 0.75f * s0[qx], tA1 = 0.75f * s0[qx] + 0.25f * s0[cp];
  float tB0 = 0.25f * s1[cm] + 0.75f * s1[qx], tB1 = 0.75f * s1[qx] + 0.25f * s1[cp];
  float tC0 = 0.25f * s2[cm] + 0.75f * s2[qx], tC1 = 0.75f * s2[qx] + 0.25f * s2[cp];
  *(float2*)dst = make_float2(0.25f * tA0 + 0.75f * tB0, 0.25f * tA1 + 0.75f * tB1);
  *(float2*)(dst + pitch) = make_float2(0.75f * tB0 + 0.25f * tC0, 0.75f * tB1 + 0.25f * tC1);
}

// 2x upsample of TWO adjacent quads (qx0 even): 4-wide x 2-row patch, float4 stores.
__device__ __forceinline__ void up_quad2(const float* __restrict__ s0,
                                         const float* __restrict__ s1,
                                         const float* __restrict__ s2,
                                         int qx0, int W, float* __restrict__ dst, int pitch) {
  int cm = qx0 > 0 ? qx0 - 1 : 0;
  int c2 = qx0 + 2 < W ? qx0 + 2 : W - 1;
  float Am = s0[cm], A0 = s0[qx0], A1 = s0[qx0 + 1], A2 = s0[c2];
  float Bm = s1[cm], B0 = s1[qx0], B1 = s1[qx0 + 1], B2 = s1[c2];
  float Cm = s2[cm], C0 = s2[qx0], C1 = s2[qx0 + 1], C2 = s2[c2];
  float hA0 = 0.25f * Am + 0.75f * A0, hA1 = 0.75f * A0 + 0.25f * A1;
  float hA2 = 0.25f * A0 + 0.75f * A1, hA3 = 0.75f * A1 + 0.25f * A2;
  float hB0 = 0.25f * Bm + 0.75f * B0, hB1 = 0.75f * B0 + 0.25f * B1;
  float hB2 = 0.25f * B0 + 0.75f * B1, hB3 = 0.75f * B1 + 0.25f * B2;
  float hC0 = 0.25f * Cm + 0.75f * C0, hC1 = 0.75f * C0 + 0.25f * C1;
  float hC2 = 0.25f * C0 + 0.75f * C1, hC3 = 0.75f * C1 + 0.25f * C2;
  *(float4*)dst = make_float4(0.25f * hA0 + 0.75f * hB0, 0.25f * hA1 + 0.75f * hB1,
                              0.25f * hA2 + 0.75f * hB2, 0.25f * hA3 + 0.75f * hB3);
  *(float4*)(dst + pitch) = make_float4(0.75f * hB0 + 0.25f * hC0, 0.75f * hB1 + 0.25f * hC1,
                                        0.75f * hB2 + 0.25f * hC2, 0.75f * hB3 + 0.25f * hC3);
}

struct P1M { float ct[32][252]; int inv[4][32]; };  // 32768 B
struct C2M { float ct[64][126]; };                  // 32256 B
struct C3M { float ct[64][49]; };                   // 12544 B
union SmemM { P1M p1; C2M c2; C3M c3; };

// Balanced XCD-local decode (see R13): b gets XCD b%8; all wpb works of a
// batch share one XCD; every XCD gets equal share of every segment.
__device__ __forceinline__ int2 xcd_decode(int d, int wpb_log) {
  int xcd = d & 7;
  int i = (d >> 3) & ((1 << wpb_log) - 1);
  int b = (((d >> (3 + wpb_log)) << 3) | xcd);
  return make_int2(b, i);
}

// ---------------------------------------------------------------------------
// fused_all: ONE launch, 1216 blocks x 256 thr.
// Och-merged waves dedup B-fragments (B independent of output channel):
//  [0,128)     conv4: wave=64 och (M=4), block=256 och. B-dup 4x -> 1x.
//  [128,640)   perm1: block=32 och (M=2) x 7-row chunk. B-dup 4x -> 2x.
//  [640,896)   conv2: block=64 och (M=2 per wave) x 7-row chunk. 4x -> 2x.
//  [896,1152)  conv3: unchanged (64 och, M=1).
//  [1152,1216) copies.
// ---------------------------------------------------------------------------
__global__ void __launch_bounds__(256)
fused_all(const float* __restrict__ f1, const float* __restrict__ f2,
          const float* __restrict__ f3, const float* __restrict__ f4,
          const float* __restrict__ cw1, const float* __restrict__ cb1,
          const float* __restrict__ cw2, const float* __restrict__ cb2,
          const float* __restrict__ cw3, const float* __restrict__ cb3,
          const float* __restrict__ cw4, const float* __restrict__ cb4,
          const float* __restrict__ xf, const float* __restrict__ w1,
          const float* __restrict__ w2, const float* __restrict__ w3,
          const float* __restrict__ w4s, const int* __restrict__ perms,
          float* __restrict__ out) {
  __shared__ SmemM sm;
  const int raw = blockIdx.x, tid = threadIdx.x;
  const int wave = tid >> 6, lane = tid & 63;
  const int l15 = lane & 15, lg = lane >> 4;
  float* o_aux1 = out + 32768;
  float* o_aux2 = o_aux1 + 12845056;
  float* o_aux3 = o_aux2 + 6422528;
  float* o_aux4 = o_aux3 + 3211264;

  if (raw < 128) {
    // ================= conv4 (wpb=2 m-halves; wave = 64 och) ===============
    int2 bi = xcd_decode(raw, 1);
    const int b = bi.x;
    const int ob = bi.y * 256 + wave * 64;
    const float* f4b = f4 + (size_t)b * 25088;

    f32x4 acc[4][4];
#pragma unroll
    for (int mi = 0; mi < 4; ++mi) {
      float bv0 = cb4[ob + mi * 16 + lg * 4 + 0], bv1 = cb4[ob + mi * 16 + lg * 4 + 1];
      float bv2 = cb4[ob + mi * 16 + lg * 4 + 2], bv3 = cb4[ob + mi * 16 + lg * 4 + 3];
#pragma unroll
      for (int n = 0; n < 4; ++n) {
        acc[mi][n][0] = bv0; acc[mi][n][1] = bv1; acc[mi][n][2] = bv2; acc[mi][n][3] = bv3;
      }
    }
    int poff[4]; bool pok[4];
#pragma unroll
    for (int n = 0; n < 4; ++n) {
      int p = n * 16 + l15;
      pok[n] = p < 49;
      poff[n] = pok[n] ? p : 0;
    }
#pragma unroll 1
    for (int k0 = 0; k0 < 512; k0 += 32) {
      bf16x8 A0 = cfrag(cw4 + (size_t)(ob + 0 + l15) * 512 + k0 + lg * 8);
      bf16x8 A1 = cfrag(cw4 + (size_t)(ob + 16 + l15) * 512 + k0 + lg * 8);
      bf16x8 A2 = cfrag(cw4 + (size_t)(ob + 32 + l15) * 512 + k0 + lg * 8);
      bf16x8 A3 = cfrag(cw4 + (size_t)(ob + 48 + l15) * 512 + k0 + lg * 8);
      const float* fb = f4b + (size_t)(k0 + lg * 8) * 49;
      bf16x8 B0 = gfrag_guard(fb + poff[0], 49, pok[0]);
      bf16x8 B1 = gfrag_guard(fb + poff[1], 49, pok[1]);
      bf16x8 B2 = gfrag_guard(fb + poff[2], 49, pok[2]);
      bf16x8 B3 = gfrag_guard(fb + poff[3], 49, pok[3]);
      acc[0][0] = __builtin_amdgcn_mfma_f32_16x16x32_bf16(A0, B0, acc[0][0], 0, 0, 0);
      acc[0][1] = __builtin_amdgcn_mfma_f32_16x16x32_bf16(A0, B1, acc[0][1], 0, 0, 0);
      acc[0][2] = __builtin_amdgcn_mfma_f32_16x16x32_bf16(A0, B2, acc[0][2], 0, 0, 0);
      acc[0][3] = __builtin_amdgcn_mfma_f32_16x16x32_bf16(A0, B3, acc[0][3], 0, 0, 0);
      acc[1][0] = __builtin_amdgcn_mfma_f32_16x16x32_bf16(A1, B0, acc[1][0], 0, 0, 0);
      acc[1][1] = __builtin_amdgcn_mfma_f32_16x16x32_bf16(A1, B1, acc[1][1], 0, 0, 0);
      acc[1][2] = __builtin_amdgcn_mfma_f32_16x16x32_bf16(A1, B2, acc[1][2], 0, 0, 0);
      acc[1][3] = __builtin_amdgcn_mfma_f32_16x16x32_bf16(A1, B3, acc[1][3], 0, 0, 0);
      acc[2][0] = __builtin_amdgcn_mfma_f32_16x16x32_bf16(A2, B0, acc[2][0], 0, 0, 0);
      acc[2][1] = __builtin_amdgcn_mfma_f32_16x16x32_bf16(A2, B1, acc[2][1], 0, 0, 0);
      acc[2][2] = __builtin_amdgcn_mfma_f32_16x16x32_bf16(A2, B2, acc[2][2], 0, 0, 0);
      acc[2][3] = __builtin_amdgcn_mfma_f32_16x16x32_bf16(A2, B3, acc[2][3], 0, 0, 0);
      acc[3][0] = __builtin_amdgcn_mfma_f32_16x16x32_bf16(A3, B0, acc[3][0], 0, 0, 0);
      acc[3][1] = __builtin_amdgcn_mfma_f32_16x16x32_bf16(A3, B1, acc[3][1], 0, 0, 0);
      acc[3][2] = __builtin_amdgcn_mfma_f32_16x16x32_bf16(A3, B2, acc[3][2], 0, 0, 0);
      acc[3][3] = __builtin_amdgcn_mfma_f32_16x16x32_bf16(A3, B3, acc[3][3], 0, 0, 0);
    }
    float* outb = o_aux4 + (size_t)b * 25088;
#pragma unroll
    for (int mi = 0; mi < 4; ++mi) {
#pragma unroll
      for (int n = 0; n < 4; ++n) {
        int p = n * 16 + l15;
        if (p < 49) {
#pragma unroll
          for (int r = 0; r < 4; ++r) {
            int o = ob + mi * 16 + lg * 4 + r;
            outb[(size_t)o * 49 + p] = acc[mi][n][r];
          }
        }
      }
    }
  } else if (raw < 640) {
    // ================= perm1 (wpb=8: 2 och-grps x 4 row-chunks; 32 och) ====
    int2 bi = xcd_decode(raw - 128, 3);
    const int b = bi.x;
    const int o0 = (bi.y >> 2) * 32;
    const int r0 = (bi.y & 3) * 7, base = r0 - 1;
    const float* f1b = f1 + (size_t)b * 50176;

    if (tid >= 128) {
      int t2 = tid - 128;
      int i = t2 >> 5, cl = t2 & 31;
      int c = o0 + cl;
      int r = 0;
      for (int j = 0; j < 64; ++j)
        if (perms[i * 64 + j] == c) r = j;
      sm.p1.inv[i][cl] = r;
    }

    int off[4];
#pragma unroll
    for (int j = 0; j < 4; ++j) {
      int praw = wave * 64 + j * 16 + l15;
      int p = praw < 251 ? praw : 251;
      int lr = p / 28, x = p - lr * 28;
      int sr = base + lr;
      sr = sr < 0 ? 0 : (sr > 27 ? 27 : sr);
      off[j] = sr * 28 + x;
    }
    f32x4 acc[2][4];
#pragma unroll
    for (int mi = 0; mi < 2; ++mi) {
      float bv0 = cb1[o0 + mi * 16 + lg * 4 + 0], bv1 = cb1[o0 + mi * 16 + lg * 4 + 1];
      float bv2 = cb1[o0 + mi * 16 + lg * 4 + 2], bv3 = cb1[o0 + mi * 16 + lg * 4 + 3];
#pragma unroll
      for (int j = 0; j < 4; ++j) {
        acc[mi][j][0] = bv0; acc[mi][j][1] = bv1; acc[mi][j][2] = bv2; acc[mi][j][3] = bv3;
      }
    }
#pragma unroll
    for (int ks = 0; ks < 2; ++ks) {
      bf16x8 A0 = cfrag(cw1 + (size_t)(o0 + 0 + l15) * 64 + ks * 32 + lg * 8);
      bf16x8 A1 = cfrag(cw1 + (size_t)(o0 + 16 + l15) * 64 + ks * 32 + lg * 8);
      const float* fb = f1b + (size_t)(ks * 32 + lg * 8) * 784;
#pragma unroll
      for (int j = 0; j < 4; ++j) {
        bf16x8 B = gfrag(fb + off[j], 784);
        acc[0][j] = __builtin_amdgcn_mfma_f32_16x16x32_bf16(A0, B, acc[0][j], 0, 0, 0);
        acc[1][j] = __builtin_amdgcn_mfma_f32_16x16x32_bf16(A1, B, acc[1][j], 0, 0, 0);
      }
    }
#pragma unroll
    for (int mi = 0; mi < 2; ++mi)
#pragma unroll
      for (int j = 0; j < 4; ++j) {
        int praw = wave * 64 + j * 16 + l15;
        if (praw < 252) {
#pragma unroll
          for (int r = 0; r < 4; ++r) sm.p1.ct[mi * 16 + lg * 4 + r][praw] = acc[mi][j][r];
        }
      }
    __syncthreads();

    // pair-epilogue: 32 ch x 7 quad-rows x 14 pairs = 3136 units
    const size_t obase = (size_t)b * 200704;
    for (int i = tid; i < 3136; i += 256) {
      int cl = i / 98;
      int rem = i - cl * 98;
      int ly = rem / 14, pr = rem - ly * 14;
      int qx0 = 2 * pr;
      int qy = r0 + ly;
      int lr = ly + 1;
      int qi = ((qy >= 14) ? 2 : 0) + ((qx0 >= 14) ? 1 : 0);
      int j = sm.p1.inv[qi][cl];
      float* dst = o_aux1 + obase + (size_t)j * 3136 + (size_t)(2 * qy) * 56 + 2 * qx0;
      up_quad2(&sm.p1.ct[cl][(lr - 1) * 28], &sm.p1.ct[cl][lr * 28],
               &sm.p1.ct[cl][(lr + 1) * 28], qx0, 28, dst, 56);
    }
  } else if (raw < 896) {
    // ================= conv2 (wpb=4: 2 och-grps x 2 row-chunks; 64 och) ====
    int2 bi = xcd_decode(raw - 640, 2);
    const int b = bi.x;
    const int o0 = (bi.y >> 1) * 64;
    const int r0 = (bi.y & 1) * 7, base = r0 - 1;
    const int og = wave >> 1, nt = wave & 1;
    const int om = o0 + og * 32;
    const float* f2b = f2 + (size_t)b * 25088;

    int off[4];
#pragma unroll
    for (int j = 0; j < 4; ++j) {
      int praw = nt * 64 + j * 16 + l15;
      int p = praw < 125 ? praw : 125;
      int lr = p / 14, x = p - lr * 14;
      int sr = base + lr;
      sr = sr < 0 ? 0 : (sr > 13 ? 13 : sr);
      off[j] = sr * 14 + x;
    }
    f32x4 acc[2][4];
#pragma unroll
    for (int mi = 0; mi < 2; ++mi) {
      float bv0 = cb2[om + mi * 16 + lg * 4 + 0], bv1 = cb2[om + mi * 16 + lg * 4 + 1];
      float bv2 = cb2[om + mi * 16 + lg * 4 + 2], bv3 = cb2[om + mi * 16 + lg * 4 + 3];
#pragma unroll
      for (int j = 0; j < 4; ++j) {
        acc[mi][j][0] = bv0; acc[mi][j][1] = bv1; acc[mi][j][2] = bv2; acc[mi][j][3] = bv3;
      }
    }
#pragma unroll
    for (int ks = 0; ks < 4; ++ks) {
      bf16x8 A0 = cfrag(cw2 + (size_t)(om + 0 + l15) * 128 + ks * 32 + lg * 8);
      bf16x8 A1 = cfrag(cw2 + (size_t)(om + 16 + l15) * 128 + ks * 32 + lg * 8);
      const float* fb = f2b + (size_t)(ks * 32 + lg * 8) * 196;
#pragma unroll
      for (int j = 0; j < 4; ++j) {
        bf16x8 B = gfrag(fb + off[j], 196);
        acc[0][j] = __builtin_amdgcn_mfma_f32_16x16x32_bf16(A0, B, acc[0][j], 0, 0, 0);
        acc[1][j] = __builtin_amdgcn_mfma_f32_16x16x32_bf16(A1, B, acc[1][j], 0, 0, 0);
      }
    }
#pragma unroll
    for (int mi = 0; mi < 2; ++mi)
#pragma unroll
      for (int j = 0; j < 4; ++j) {
        int praw = nt * 64 + j * 16 + l15;
        if (praw < 126) {
#pragma unroll
          for (int r = 0; r < 4; ++r) sm.c2.ct[og * 32 + mi * 16 + lg * 4 + r][praw] = acc[mi][j][r];
        }
      }
    __syncthreads();

    // pair-epilogue: 64 ch x 7 quad-rows x 7 pairs = 3136 units
    const size_t obase = (size_t)b * 100352;
    for (int i = tid; i < 3136; i += 256) {
      int cl = i / 49;
      int rem = i - cl * 49;
      int ly = rem / 7, pr = rem - ly * 7;
      int qx0 = 2 * pr;
      int qy = r0 + ly;
      int lr = ly + 1;
      float* dst = o_aux2 + obase + (size_t)(o0 + cl) * 784 + (size_t)(2 * qy) * 28 + 2 * qx0;
      up_quad2(&sm.c2.ct[cl][(lr - 1) * 14], &sm.c2.ct[cl][lr * 14],
               &sm.c2.ct[cl][(lr + 1) * 14], qx0, 14, dst, 28);
    }
  } else if (raw < 1152) {
    // ================= conv3 (wpb=4: 4 och-grps; unchanged body) ===========
    int2 bi = xcd_decode(raw - 896, 2);
    const int b = bi.x;
    const int o0 = bi.y * 64;
    const int om = o0 + wave * 16;
    const float* f3b = f3 + (size_t)b * 6272;

    int poff[4]; bool pok[4];
#pragma unroll
    for (int j = 0; j < 4; ++j) {
      int p = j * 16 + l15;
      pok[j] = p < 49;
      poff[j] = pok[j] ? p : 0;
    }
    f32x4 acc[4];
    {
      float bv0 = cb3[om + lg * 4 + 0], bv1 = cb3[om + lg * 4 + 1];
      float bv2 = cb3[om + lg * 4 + 2], bv3 = cb3[om + lg * 4 + 3];
#pragma unroll
      for (int j = 0; j < 4; ++j) {
        acc[j][0] = bv0; acc[j][1] = bv1; acc[j][2] = bv2; acc[j][3] = bv3;
      }
    }
    const float* ap = cw3 + (size_t)(om + l15) * 128 + lg * 8;
#pragma unroll
    for (int ks = 0; ks < 4; ++ks) {
      bf16x8 A = cfrag(ap + ks * 32);
      const float* fb = f3b + (size_t)(ks * 32 + lg * 8) * 49;
#pragma unroll
      for (int j = 0; j < 4; ++j) {
        bf16x8 B = gfrag_guard(fb + poff[j], 49, pok[j]);
        acc[j] = __builtin_amdgcn_mfma_f32_16x16x32_bf16(A, B, acc[j], 0, 0, 0);
      }
    }
#pragma unroll
    for (int j = 0; j < 4; ++j) {
      int p = j * 16 + l15;
      if (p < 49) {
#pragma unroll
        for (int r = 0; r < 4; ++r) sm.c3.ct[wave * 16 + lg * 4 + r][p] = acc[j][r];
      }
    }
    __syncthreads();

    const size_t obase = (size_t)b * 50176;
    for (int i = tid; i < 64 * 49; i += 256) {
      int cl = i / 49;
      int q = i - cl * 49;
      int qy = q / 7, qx = q - qy * 7;
      int rm = qy > 0 ? qy - 1 : 0, rp = qy < 6 ? qy + 1 : 6;
      float* dst = o_aux3 + obase + (size_t)(o0 + cl) * 196 + (size_t)(2 * qy) * 14 + 2 * qx;
      up_quad_rows(&sm.c3.ct[cl][rm * 7], &sm.c3.ct[cl][qy * 7], &sm.c3.ct[cl][rp * 7],
                   qx, 7, dst, 14);
    }
  } else {
    // ================= copies =================
    int idx = (raw - 1152) * 256 + tid;
    const int stride = 64 * 256;
    float4* o4 = (float4*)out;
    const size_t W1 = 6029312;  // o_w1 offset in float4s
    for (int i = idx; i < 8192; i += stride) o4[i] = ((const float4*)xf)[i];
    for (int i = idx; i < 50176; i += stride) o4[W1 + i] = ((const float4*)w1)[i];
    for (int i = idx; i < 25088; i += stride) o4[W1 + 50176 + i] = ((const float4*)w2)[i];
    for (int i = idx; i < 12544; i += stride) o4[W1 + 75264 + i] = ((const float4*)w3)[i];
    for (int i = idx; i < 6272; i += stride) o4[W1 + 87808 + i] = ((const float4*)w4s)[i];
  }
}

extern "C" void kernel_launch(void* const* d_in, const int* in_sizes, int n_in,
                              void* d_out, int out_size, void* d_ws, size_t ws_size,
                              hipStream_t stream) {
  const float* f1      = (const float*)d_in[0];
  const float* f2      = (const float*)d_in[1];
  const float* f3      = (const float*)d_in[2];
  const float* f4      = (const float*)d_in[3];
  const float* x_final = (const float*)d_in[4];
  const float* cw1     = (const float*)d_in[5];
  const float* cb1     = (const float*)d_in[6];
  const float* cw2     = (const float*)d_in[7];
  const float* cb2     = (const float*)d_in[8];
  const float* cw3     = (const float*)d_in[9];
  const float* cb3     = (const float*)d_in[10];
  const float* cw4     = (const float*)d_in[11];
  const float* cb4     = (const float*)d_in[12];
  const float* w1      = (const float*)d_in[13];
  const float* w2      = (const float*)d_in[14];
  const float* w3      = (const float*)d_in[15];
  const float* w4      = (const float*)d_in[16];
  const int*   perms   = (const int*)d_in[17];

  float* out = (float*)d_out;

  fused_all<<<1216, 256, 0, stream>>>(f1, f2, f3, f4, cw1, cb1, cw2, cb2,
                                      cw3, cb3, cw4, cb4, x_final, w1, w2, w3, w4,
                                      perms, out);
}

// Round 15
// 48.917 us; speedup vs baseline: 1.0481x; 1.0481x over previous
//
#include <hip/hip_runtime.h>
#include <hip/hip_bf16.h>
#include <cstddef>

typedef __attribute__((ext_vector_type(8))) short bf16x8;
typedef __attribute__((ext_vector_type(4))) float f32x4;

__device__ __forceinline__ float4 ld4(const float* p) { return *(const float4*)p; }
__device__ __forceinline__ unsigned short f2bf(float v) {
  __hip_bfloat16 h = __float2bfloat16(v);
  return *(unsigned short*)&h;
}

__device__ __forceinline__ bf16x8 pack8(float v0, float v1, float v2, float v3,
                                        float v4, float v5, float v6, float v7) {
  bf16x8 r;
  r[0] = (short)f2bf(v0); r[1] = (short)f2bf(v1);
  r[2] = (short)f2bf(v2); r[3] = (short)f2bf(v3);
  r[4] = (short)f2bf(v4); r[5] = (short)f2bf(v5);
  r[6] = (short)f2bf(v6); r[7] = (short)f2bf(v7);
  return r;
}
// 8 contiguous fp32 -> bf16x8 (A-fragments: weight rows)
__device__ __forceinline__ bf16x8 cfrag(const float* __restrict__ p) {
  float4 a = ld4(p), b = ld4(p + 4);
  return pack8(a.x, a.y, a.z, a.w, b.x, b.y, b.z, b.w);
}
// 8 strided fp32 -> bf16x8 (B-fragments: input channel walk at fixed pixel)
__device__ __forceinline__ bf16x8 gfrag(const float* __restrict__ p, int stride) {
  float v0 = p[0], v1 = p[stride], v2 = p[2 * stride], v3 = p[3 * stride];
  float v4 = p[4 * stride], v5 = p[5 * stride], v6 = p[6 * stride], v7 = p[7 * stride];
  return pack8(v0, v1, v2, v3, v4, v5, v6, v7);
}
__device__ __forceinline__ bf16x8 gfrag_guard(const float* __restrict__ p, int stride, bool ok) {
  float v0 = ok ? p[0] : 0.f, v1 = ok ? p[stride] : 0.f;
  float v2 = ok ? p[2 * stride] : 0.f, v3 = ok ? p[3 * stride] : 0.f;
  float v4 = ok ? p[4 * stride] : 0.f, v5 = ok ? p[5 * stride] : 0.f;
  float v6 = ok ? p[6 * stride] : 0.f, v7 = ok ? p[7 * stride] : 0.f;
  return pack8(v0, v1, v2, v3, v4, v5, v6, v7);
}

// 2x bilinear upsample of one 2x2 quad (three halo-resolved source rows).
__device__ __forceinline__ void up_quad_rows(const float* __restrict__ s0,
                                             const float* __restrict__ s1,
                                             const float* __restrict__ s2,
                                             int qx, int W, float* __restrict__ dst, int pitch) {
  int cm = qx > 0 ? qx - 1 : 0, cp = qx < W - 1 ? qx + 1 : W - 1;
  float tA0 = 0.25f * s0[cm] + 0.75f * s0[qx], tA1 = 0.75f * s0[qx] + 0.25f * s0[cp];
  float tB0 = 0.25f * s1[cm] + 0.75f * s1[qx], tB1 = 0.75f * s1[qx] + 0.25f * s1[cp];
  float tC0 = 0.25f * s2[cm] + 0.75f * s2[qx], tC1 = 0.75f * s2[qx] + 0.25f * s2[cp];
  *(float2*)dst = make_float2(0.25f * tA0 + 0.75f * tB0, 0.25f * tA1 + 0.75f * tB1);
  *(float2*)(dst + pitch) = make_float2(0.75f * tB0 + 0.25f * tC0, 0.75f * tB1 + 0.25f * tC1);
}

// 2x upsample of TWO adjacent quads (qx0 even): 4-wide x 2-row patch, float4 stores.
__device__ __forceinline__ void up_quad2(const float* __restrict__ s0,
                                         const float* __restrict__ s1,
                                         const float* __restrict__ s2,
                                         int qx0, int W, float* __restrict__ dst, int pitch) {
  int cm = qx0 > 0 ? qx0 - 1 : 0;
  int c2 = qx0 + 2 < W ? qx0 + 2 : W - 1;
  float Am = s0[cm], A0 = s0[qx0], A1 = s0[qx0 + 1], A2 = s0[c2];
  float Bm = s1[cm], B0 = s1[qx0], B1 = s1[qx0 + 1], B2 = s1[c2];
  float Cm = s2[cm], C0 = s2[qx0], C1 = s2[qx0 + 1], C2 = s2[c2];
  float hA0 = 0.25f * Am + 0.75f * A0, hA1 = 0.75f * A0 + 0.25f * A1;
  float hA2 = 0.25f * A0 + 0.75f * A1, hA3 = 0.75f * A1 + 0.25f * A2;
  float hB0 = 0.25f * Bm + 0.75f * B0, hB1 = 0.75f * B0 + 0.25f * B1;
  float hB2 = 0.25f * B0 + 0.75f * B1, hB3 = 0.75f * B1 + 0.25f * B2;
  float hC0 = 0.25f * Cm + 0.75f * C0, hC1 = 0.75f * C0 + 0.25f * C1;
  float hC2 = 0.25f * C0 + 0.75f * C1, hC3 = 0.75f * C1 + 0.25f * C2;
  *(float4*)dst = make_float4(0.25f * hA0 + 0.75f * hB0, 0.25f * hA1 + 0.75f * hB1,
                              0.25f * hA2 + 0.75f * hB2, 0.25f * hA3 + 0.75f * hB3);
  *(float4*)(dst + pitch) = make_float4(0.75f * hB0 + 0.25f * hC0, 0.75f * hB1 + 0.25f * hC1,
                                        0.75f * hB2 + 0.25f * hC2, 0.75f * hB3 + 0.25f * hC3);
}

struct P1M { float ct[16][252]; int inv[4][16]; };  // R13 sizes (16.4 KB max union)
struct C2M { float ct[32][126]; };
struct C3M { float ct[64][49]; };
union SmemM { P1M p1; C2M c2; C3M c3; };

// Balanced XCD-local decode: b gets XCD b%8; all wpb works of a batch share
// one XCD (panel L2 reuse); every XCD gets an equal share of every segment.
__device__ __forceinline__ int2 xcd_decode(int d, int wpb_log) {
  int xcd = d & 7;
  int i = (d >> 3) & ((1 << wpb_log) - 1);
  int b = (((d >> (3 + wpb_log)) << 3) | xcd);
  return make_int2(b, i);
}

// ---------------------------------------------------------------------------
// fused_all: ONE launch, 1984 blocks x 256 thr (single resident generation).
//  [0,128)     conv4: wave=64 och (M=4, B-dedup), 2 m-halves/batch [R14 body]
//  [128,1152)  perm1: 16 och x 7-row chunk [R13 body]
//  [1152,1664) conv2: 32 och x 7-row chunk [R13 body]
//  [1664,1920) conv3: 64 och [R13 body]
//  [1920,1984) copies
// ---------------------------------------------------------------------------
__global__ void __launch_bounds__(256)
fused_all(const float* __restrict__ f1, const float* __restrict__ f2,
          const float* __restrict__ f3, const float* __restrict__ f4,
          const float* __restrict__ cw1, const float* __restrict__ cb1,
          const float* __restrict__ cw2, const float* __restrict__ cb2,
          const float* __restrict__ cw3, const float* __restrict__ cb3,
          const float* __restrict__ cw4, const float* __restrict__ cb4,
          const float* __restrict__ xf, const float* __restrict__ w1,
          const float* __restrict__ w2, const float* __restrict__ w3,
          const float* __restrict__ w4s, const int* __restrict__ perms,
          float* __restrict__ out) {
  __shared__ SmemM sm;
  const int raw = blockIdx.x, tid = threadIdx.x;
  const int wave = tid >> 6, lane = tid & 63;
  const int l15 = lane & 15, lg = lane >> 4;
  float* o_aux1 = out + 32768;
  float* o_aux2 = o_aux1 + 12845056;
  float* o_aux3 = o_aux2 + 6422528;
  float* o_aux4 = o_aux3 + 3211264;

  if (raw < 128) {
    // ================= conv4 (R14 body: wave = 64 och, B built once) =======
    int2 bi = xcd_decode(raw, 1);
    const int b = bi.x;
    const int ob = bi.y * 256 + wave * 64;
    const float* f4b = f4 + (size_t)b * 25088;

    f32x4 acc[4][4];
#pragma unroll
    for (int mi = 0; mi < 4; ++mi) {
      float bv0 = cb4[ob + mi * 16 + lg * 4 + 0], bv1 = cb4[ob + mi * 16 + lg * 4 + 1];
      float bv2 = cb4[ob + mi * 16 + lg * 4 + 2], bv3 = cb4[ob + mi * 16 + lg * 4 + 3];
#pragma unroll
      for (int n = 0; n < 4; ++n) {
        acc[mi][n][0] = bv0; acc[mi][n][1] = bv1; acc[mi][n][2] = bv2; acc[mi][n][3] = bv3;
      }
    }
    int poff[4]; bool pok[4];
#pragma unroll
    for (int n = 0; n < 4; ++n) {
      int p = n * 16 + l15;
      pok[n] = p < 49;
      poff[n] = pok[n] ? p : 0;
    }
#pragma unroll 1
    for (int k0 = 0; k0 < 512; k0 += 32) {
      bf16x8 A0 = cfrag(cw4 + (size_t)(ob + 0 + l15) * 512 + k0 + lg * 8);
      bf16x8 A1 = cfrag(cw4 + (size_t)(ob + 16 + l15) * 512 + k0 + lg * 8);
      bf16x8 A2 = cfrag(cw4 + (size_t)(ob + 32 + l15) * 512 + k0 + lg * 8);
      bf16x8 A3 = cfrag(cw4 + (size_t)(ob + 48 + l15) * 512 + k0 + lg * 8);
      const float* fb = f4b + (size_t)(k0 + lg * 8) * 49;
      bf16x8 B0 = gfrag_guard(fb + poff[0], 49, pok[0]);
      bf16x8 B1 = gfrag_guard(fb + poff[1], 49, pok[1]);
      bf16x8 B2 = gfrag_guard(fb + poff[2], 49, pok[2]);
      bf16x8 B3 = gfrag_guard(fb + poff[3], 49, pok[3]);
      acc[0][0] = __builtin_amdgcn_mfma_f32_16x16x32_bf16(A0, B0, acc[0][0], 0, 0, 0);
      acc[0][1] = __builtin_amdgcn_mfma_f32_16x16x32_bf16(A0, B1, acc[0][1], 0, 0, 0);
      acc[0][2] = __builtin_amdgcn_mfma_f32_16x16x32_bf16(A0, B2, acc[0][2], 0, 0, 0);
      acc[0][3] = __builtin_amdgcn_mfma_f32_16x16x32_bf16(A0, B3, acc[0][3], 0, 0, 0);
      acc[1][0] = __builtin_amdgcn_mfma_f32_16x16x32_bf16(A1, B0, acc[1][0], 0, 0, 0);
      acc[1][1] = __builtin_amdgcn_mfma_f32_16x16x32_bf16(A1, B1, acc[1][1], 0, 0, 0);
      acc[1][2] = __builtin_amdgcn_mfma_f32_16x16x32_bf16(A1, B2, acc[1][2], 0, 0, 0);
      acc[1][3] = __builtin_amdgcn_mfma_f32_16x16x32_bf16(A1, B3, acc[1][3], 0, 0, 0);
      acc[2][0] = __builtin_amdgcn_mfma_f32_16x16x32_bf16(A2, B0, acc[2][0], 0, 0, 0);
      acc[2][1] = __builtin_amdgcn_mfma_f32_16x16x32_bf16(A2, B1, acc[2][1], 0, 0, 0);
      acc[2][2] = __builtin_amdgcn_mfma_f32_16x16x32_bf16(A2, B2, acc[2][2], 0, 0, 0);
      acc[2][3] = __builtin_amdgcn_mfma_f32_16x16x32_bf16(A2, B3, acc[2][3], 0, 0, 0);
      acc[3][0] = __builtin_amdgcn_mfma_f32_16x16x32_bf16(A3, B0, acc[3][0], 0, 0, 0);
      acc[3][1] = __builtin_amdgcn_mfma_f32_16x16x32_bf16(A3, B1, acc[3][1], 0, 0, 0);
      acc[3][2] = __builtin_amdgcn_mfma_f32_16x16x32_bf16(A3, B2, acc[3][2], 0, 0, 0);
      acc[3][3] = __builtin_amdgcn_mfma_f32_16x16x32_bf16(A3, B3, acc[3][3], 0, 0, 0);
    }
    float* outb = o_aux4 + (size_t)b * 25088;
#pragma unroll
    for (int mi = 0; mi < 4; ++mi) {
#pragma unroll
      for (int n = 0; n < 4; ++n) {
        int p = n * 16 + l15;
        if (p < 49) {
#pragma unroll
          for (int r = 0; r < 4; ++r) {
            int o = ob + mi * 16 + lg * 4 + r;
            outb[(size_t)o * 49 + p] = acc[mi][n][r];
          }
        }
      }
    }
  } else if (raw < 1152) {
    // ================= perm1 (R13 body: 16 och, 7-row chunk) ===============
    int2 bi = xcd_decode(raw - 128, 4);
    const int b = bi.x;
    const int o0 = (bi.y >> 2) * 16;
    const int r0 = (bi.y & 3) * 7, base = r0 - 1;
    const float* f1b = f1 + (size_t)b * 50176;

    if (tid >= 128 && tid < 192) {
      int t2 = tid - 128;
      int i = t2 >> 4, cl = t2 & 15;
      int c = o0 + cl;
      int r = 0;
      for (int j = 0; j < 64; ++j)
        if (perms[i * 64 + j] == c) r = j;
      sm.p1.inv[i][cl] = r;
    }

    int off[4];
#pragma unroll
    for (int j = 0; j < 4; ++j) {
      int praw = wave * 64 + j * 16 + l15;
      int p = praw < 251 ? praw : 251;
      int lr = p / 28, x = p - lr * 28;
      int sr = base + lr;
      sr = sr < 0 ? 0 : (sr > 27 ? 27 : sr);
      off[j] = sr * 28 + x;
    }
    f32x4 acc[4];
    {
      float bv0 = cb1[o0 + lg * 4 + 0], bv1 = cb1[o0 + lg * 4 + 1];
      float bv2 = cb1[o0 + lg * 4 + 2], bv3 = cb1[o0 + lg * 4 + 3];
#pragma unroll
      for (int j = 0; j < 4; ++j) {
        acc[j][0] = bv0; acc[j][1] = bv1; acc[j][2] = bv2; acc[j][3] = bv3;
      }
    }
    const float* ap = cw1 + (size_t)(o0 + l15) * 64 + lg * 8;
#pragma unroll
    for (int ks = 0; ks < 2; ++ks) {
      bf16x8 A = cfrag(ap + ks * 32);
      const float* fb = f1b + (size_t)(ks * 32 + lg * 8) * 784;
#pragma unroll
      for (int j = 0; j < 4; ++j) {
        bf16x8 B = gfrag(fb + off[j], 784);
        acc[j] = __builtin_amdgcn_mfma_f32_16x16x32_bf16(A, B, acc[j], 0, 0, 0);
      }
    }
#pragma unroll
    for (int j = 0; j < 4; ++j) {
      int praw = wave * 64 + j * 16 + l15;
      if (praw < 252) {
#pragma unroll
        for (int r = 0; r < 4; ++r) sm.p1.ct[lg * 4 + r][praw] = acc[j][r];
      }
    }
    __syncthreads();

    const size_t obase = (size_t)b * 200704;
    for (int i = tid; i < 1568; i += 256) {
      int cl = i / 98;
      int rem = i - cl * 98;
      int ly = rem / 14, pr = rem - ly * 14;
      int qx0 = 2 * pr;
      int qy = r0 + ly;
      int lr = ly + 1;
      int qi = ((qy >= 14) ? 2 : 0) + ((qx0 >= 14) ? 1 : 0);
      int j = sm.p1.inv[qi][cl];
      float* dst = o_aux1 + obase + (size_t)j * 3136 + (size_t)(2 * qy) * 56 + 2 * qx0;
      up_quad2(&sm.p1.ct[cl][(lr - 1) * 28], &sm.p1.ct[cl][lr * 28],
               &sm.p1.ct[cl][(lr + 1) * 28], qx0, 28, dst, 56);
    }
  } else if (raw < 1664) {
    // ================= conv2 (R13 body: 32 och, 7-row chunk) ===============
    int2 bi = xcd_decode(raw - 1152, 3);
    const int b = bi.x;
    const int o0 = (bi.y >> 1) * 32;
    const int r0 = (bi.y & 1) * 7, base = r0 - 1;
    const int og = wave >> 1, nt = wave & 1;
    const int om = o0 + og * 16;
    const float* f2b = f2 + (size_t)b * 25088;

    int off[4];
#pragma unroll
    for (int j = 0; j < 4; ++j) {
      int praw = nt * 64 + j * 16 + l15;
      int p = praw < 125 ? praw : 125;
      int lr = p / 14, x = p - lr * 14;
      int sr = base + lr;
      sr = sr < 0 ? 0 : (sr > 13 ? 13 : sr);
      off[j] = sr * 14 + x;
    }
    f32x4 acc[4];
    {
      float bv0 = cb2[om + lg * 4 + 0], bv1 = cb2[om + lg * 4 + 1];
      float bv2 = cb2[om + lg * 4 + 2], bv3 = cb2[om + lg * 4 + 3];
#pragma unroll
      for (int j = 0; j < 4; ++j) {
        acc[j][0] = bv0; acc[j][1] = bv1; acc[j][2] = bv2; acc[j][3] = bv3;
      }
    }
    const float* ap = cw2 + (size_t)(om + l15) * 128 + lg * 8;
#pragma unroll
    for (int ks = 0; ks < 4; ++ks) {
      bf16x8 A = cfrag(ap + ks * 32);
      const float* fb = f2b + (size_t)(ks * 32 + lg * 8) * 196;
#pragma unroll
      for (int j = 0; j < 4; ++j) {
        bf16x8 B = gfrag(fb + off[j], 196);
        acc[j] = __builtin_amdgcn_mfma_f32_16x16x32_bf16(A, B, acc[j], 0, 0, 0);
      }
    }
#pragma unroll
    for (int j = 0; j < 4; ++j) {
      int praw = nt * 64 + j * 16 + l15;
      if (praw < 126) {
#pragma unroll
        for (int r = 0; r < 4; ++r) sm.c2.ct[og * 16 + lg * 4 + r][praw] = acc[j][r];
      }
    }
    __syncthreads();

    const size_t obase = (size_t)b * 100352;
    for (int i = tid; i < 1568; i += 256) {
      int cl = i / 49;
      int rem = i - cl * 49;
      int ly = rem / 7, pr = rem - ly * 7;
      int qx0 = 2 * pr;
      int qy = r0 + ly;
      int lr = ly + 1;
      float* dst = o_aux2 + obase + (size_t)(o0 + cl) * 784 + (size_t)(2 * qy) * 28 + 2 * qx0;
      up_quad2(&sm.c2.ct[cl][(lr - 1) * 14], &sm.c2.ct[cl][lr * 14],
               &sm.c2.ct[cl][(lr + 1) * 14], qx0, 14, dst, 28);
    }
  } else if (raw < 1920) {
    // ================= conv3 (R13 body: 64 och) ============================
    int2 bi = xcd_decode(raw - 1664, 2);
    const int b = bi.x;
    const int o0 = bi.y * 64;
    const int om = o0 + wave * 16;
    const float* f3b = f3 + (size_t)b * 6272;

    int poff[4]; bool pok[4];
#pragma unroll
    for (int j = 0; j < 4; ++j) {
      int p = j * 16 + l15;
      pok[j] = p < 49;
      poff[j] = pok[j] ? p : 0;
    }
    f32x4 acc[4];
    {
      float bv0 = cb3[om + lg * 4 + 0], bv1 = cb3[om + lg * 4 + 1];
      float bv2 = cb3[om + lg * 4 + 2], bv3 = cb3[om + lg * 4 + 3];
#pragma unroll
      for (int j = 0; j < 4; ++j) {
        acc[j][0] = bv0; acc[j][1] = bv1; acc[j][2] = bv2; acc[j][3] = bv3;
      }
    }
    const float* ap = cw3 + (size_t)(om + l15) * 128 + lg * 8;
#pragma unroll
    for (int ks = 0; ks < 4; ++ks) {
      bf16x8 A = cfrag(ap + ks * 32);
      const float* fb = f3b + (size_t)(ks * 32 + lg * 8) * 49;
#pragma unroll
      for (int j = 0; j < 4; ++j) {
        bf16x8 B = gfrag_guard(fb + poff[j], 49, pok[j]);
        acc[j] = __builtin_amdgcn_mfma_f32_16x16x32_bf16(A, B, acc[j], 0, 0, 0);
      }
    }
#pragma unroll
    for (int j = 0; j < 4; ++j) {
      int p = j * 16 + l15;
      if (p < 49) {
#pragma unroll
        for (int r = 0; r < 4; ++r) sm.c3.ct[wave * 16 + lg * 4 + r][p] = acc[j][r];
      }
    }
    __syncthreads();

    const size_t obase = (size_t)b * 50176;
    for (int i = tid; i < 64 * 49; i += 256) {
      int cl = i / 49;
      int q = i - cl * 49;
      int qy = q / 7, qx = q - qy * 7;
      int rm = qy > 0 ? qy - 1 : 0, rp = qy < 6 ? qy + 1 : 6;
      float* dst = o_aux3 + obase + (size_t)(o0 + cl) * 196 + (size_t)(2 * qy) * 14 + 2 * qx;
      up_quad_rows(&sm.c3.ct[cl][rm * 7], &sm.c3.ct[cl][qy * 7], &sm.c3.ct[cl][rp * 7],
                   qx, 7, dst, 14);
    }
  } else {
    // ================= copies =================
    int idx = (raw - 1920) * 256 + tid;
    const int stride = 64 * 256;
    float4* o4 = (float4*)out;
    const size_t W1 = 6029312;  // o_w1 offset in float4s
    for (int i = idx; i < 8192; i += stride) o4[i] = ((const float4*)xf)[i];
    for (int i = idx; i < 50176; i += stride) o4[W1 + i] = ((const float4*)w1)[i];
    for (int i = idx; i < 25088; i += stride) o4[W1 + 50176 + i] = ((const float4*)w2)[i];
    for (int i = idx; i < 12544; i += stride) o4[W1 + 75264 + i] = ((const float4*)w3)[i];
    for (int i = idx; i < 6272; i += stride) o4[W1 + 87808 + i] = ((const float4*)w4s)[i];
  }
}

extern "C" void kernel_launch(void* const* d_in, const int* in_sizes, int n_in,
                              void* d_out, int out_size, void* d_ws, size_t ws_size,
                              hipStream_t stream) {
  const float* f1      = (const float*)d_in[0];
  const float* f2      = (const float*)d_in[1];
  const float* f3      = (const float*)d_in[2];
  const float* f4      = (const float*)d_in[3];
  const float* x_final = (const float*)d_in[4];
  const float* cw1     = (const float*)d_in[5];
  const float* cb1     = (const float*)d_in[6];
  const float* cw2     = (const float*)d_in[7];
  const float* cb2     = (const float*)d_in[8];
  const float* cw3     = (const float*)d_in[9];
  const float* cb3     = (const float*)d_in[10];
  const float* cw4     = (const float*)d_in[11];
  const float* cb4     = (const float*)d_in[12];
  const float* w1      = (const float*)d_in[13];
  const float* w2      = (const float*)d_in[14];
  const float* w3      = (const float*)d_in[15];
  const float* w4      = (const float*)d_in[16];
  const int*   perms   = (const int*)d_in[17];

  float* out = (float*)d_out;

  fused_all<<<1984, 256, 0, stream>>>(f1, f2, f3, f4, cw1, cb1, cw2, cb2,
                                      cw3, cb3, cw4, cb4, x_final, w1, w2, w3, w4,
                                      perms, out);
}